// Round 6
// baseline (398.167 us; speedup 1.0000x reference)
//
#include <hip/hip_runtime.h>

#define BATCH   32
#define DIM     128
#define NBASES  8
#define SSTEPS  128
#define MAT     (DIM*DIM)
#define NELEM   (BATCH*MAT)

// ---- per-batch scratch in device globals (.bss, 18 MB). Each buffer is fully
// written before it is read within a call (no stale-L1 hazard: first touch is
// a store, which bypasses L1; first load pulls from L2). ----
__device__ __align__(16) float g_rs[NELEM];
__device__ __align__(16) float g_ks[NELEM];
__device__ __align__(16) float g_X [NELEM];
__device__ __align__(16) float g_X2[NELEM];
__device__ __align__(16) float g_c0[NELEM];   // M^T
__device__ __align__(16) float g_c1[NELEM];   // (M^2)^T
__device__ __align__(16) float g_c2[NELEM];   // (M^4)^T
__device__ __align__(16) float g_c3[NELEM];   // (M^8)^T
__device__ __align__(16) float g_c4[NELEM];   // (M^16)^T

// ---- per-block full 128x128x128 f32 matmul, 1024 threads, 4x4 reg tile ----
// thread t: rows r0..r0+3 (r0=(t>>5)*4, half-wave uniform -> A loads broadcast),
//           cols c0..c0+3 (float4 B loads, coalesced).
// POLYA: A(r,k) = fa0*I + fa1*X + fa2*X2  (formed on the fly)
// EPI:   O += ea0*I + ea1*X
// TRANS: transposed store (O[c,r]) -> chain holds M^T
template<bool POLYA, bool EPI, bool TRANS>
__device__ __forceinline__ void mm_full(
    const float* __restrict__ A, const float* __restrict__ Bm, float* __restrict__ O,
    const float* __restrict__ Xb, const float* __restrict__ X2b,
    float fa0, float fa1, float fa2, float ea0, float ea1, int t)
{
    const int r0 = (t >> 5) * 4;
    const int c0 = (t & 31) * 4;
    float acc[4][4];
    #pragma unroll
    for (int i = 0; i < 4; ++i)
        #pragma unroll
        for (int j = 0; j < 4; ++j) acc[i][j] = 0.f;
    for (int k = 0; k < DIM; ++k) {
        const float4 bv = *reinterpret_cast<const float4*>(Bm + k * DIM + c0);
        #pragma unroll
        for (int i = 0; i < 4; ++i) {
            const int r = r0 + i;
            float a;
            if (POLYA) {
                a = fa1 * Xb[r * DIM + k] + fa2 * X2b[r * DIM + k];
                if (k == r) a += fa0;
            } else {
                a = A[r * DIM + k];
            }
            acc[i][0] += a * bv.x; acc[i][1] += a * bv.y;
            acc[i][2] += a * bv.z; acc[i][3] += a * bv.w;
        }
    }
    #pragma unroll
    for (int i = 0; i < 4; ++i) {
        const int r = r0 + i;
        #pragma unroll
        for (int j = 0; j < 4; ++j) {
            const int cc = c0 + j;
            float v = acc[i][j];
            if (EPI) {
                v += ea1 * Xb[r * DIM + cc];
                if (r == cc) v += ea0;
            }
            if (TRANS) O[cc * DIM + r] = v;
            else       O[r * DIM + cc] = v;
        }
    }
}

__device__ __forceinline__ void write_out(float* __restrict__ outF, int b, int sidx,
                                          int o, int c, float val,
                                          int interleaved, int out_size)
{
    if (interleaved) {
        const int oi = ((b * SSTEPS + sidx) * DIM + o) * 2 + c;
        if (oi < out_size) outF[oi] = val;
    } else if (c == 0) {
        const int oi = (b * SSTEPS + sidx) * DIM + o;
        if (oi < out_size) outF[oi] = val;
    }
}

// ================= the whole problem, one kernel, 1 block = 1 batch =================
__global__ __launch_bounds__(1024)
void htg_fused(const float* __restrict__ z0r, const float* __restrict__ z0i,
               const float* __restrict__ ts,  const float* __restrict__ kco,
               const float* __restrict__ rco, const float* __restrict__ alp,
               const float* __restrict__ bet, const float* __restrict__ KB,
               const float* __restrict__ RB,  float* __restrict__ outF,
               int interleaved, int out_size)
{
    const int b = blockIdx.x, t = threadIdx.x;
    __shared__ float s_W[MAT];            // 64 KB: (M^16)^T resident
    __shared__ float s_u[2 * 16 * DIM];   // 16 KB: rolling u-window, slot (c,v)
    __shared__ float s_z[2 * DIM];        // 1 KB

    float* rs  = g_rs + b * MAT;
    float* ks  = g_ks + b * MAT;
    float* X   = g_X  + b * MAT;
    float* X2  = g_X2 + b * MAT;
    float* c0b = g_c0 + b * MAT;
    float* c1b = g_c1 + b * MAT;
    float* c2b = g_c2 + b * MAT;
    float* c3b = g_c3 + b * MAT;
    float* c4b = g_c4 + b * MAT;

    // ---- S1: Rsum/Ksum basis contractions (flat float4, perfectly coalesced) ----
    {
        float rc[NBASES], kc[NBASES];
        #pragma unroll
        for (int n = 0; n < NBASES; ++n) {
            rc[n] = rco[b * NBASES + n];
            kc[n] = kco[b * NBASES + n];
        }
        #pragma unroll
        for (int q = 0; q < 4; ++q) {
            const int e = q * 4096 + t * 4;
            float4 r4 = {0.f, 0.f, 0.f, 0.f}, k4 = {0.f, 0.f, 0.f, 0.f};
            #pragma unroll
            for (int n = 0; n < NBASES; ++n) {
                const float4 rv = *reinterpret_cast<const float4*>(RB + n * MAT + e);
                const float4 kv = *reinterpret_cast<const float4*>(KB + n * MAT + e);
                r4.x += rc[n] * rv.x; r4.y += rc[n] * rv.y;
                r4.z += rc[n] * rv.z; r4.w += rc[n] * rv.w;
                k4.x += kc[n] * kv.x; k4.y += kc[n] * kv.y;
                k4.z += kc[n] * kv.z; k4.w += kc[n] * kv.w;
            }
            *reinterpret_cast<float4*>(rs + e) = r4;
            *reinterpret_cast<float4*>(ks + e) = k4;
        }
    }
    __syncthreads();

    // ---- S2: X = (alpha*skew(Ksum) - beta*(Rsum^T@Rsum)) * dt + 1e-6*I ----
    {
        const float alpha = alp[b], beta = bet[b];
        const double dt = (double)ts[0];
        const int r0 = (t >> 5) * 4, cc0 = (t & 31) * 4;
        float acc[4][4];
        #pragma unroll
        for (int i = 0; i < 4; ++i)
            #pragma unroll
            for (int j = 0; j < 4; ++j) acc[i][j] = 0.f;
        for (int k = 0; k < DIM; ++k) {
            const float4 bv = *reinterpret_cast<const float4*>(rs + k * DIM + cc0);
            #pragma unroll
            for (int i = 0; i < 4; ++i) {
                const float a = rs[k * DIM + r0 + i];   // Rsum^T operand
                acc[i][0] += a * bv.x; acc[i][1] += a * bv.y;
                acc[i][2] += a * bv.z; acc[i][3] += a * bv.w;
            }
        }
        #pragma unroll
        for (int i = 0; i < 4; ++i) {
            const int r = r0 + i;
            #pragma unroll
            for (int j = 0; j < 4; ++j) {
                const int cc = cc0 + j;
                const float ksym = ks[r * DIM + cc] - ks[cc * DIM + r];
                const float av = alpha * ksym - beta * acc[i][j];  // beta*neg_gram
                double xv = (double)av * dt;
                if (r == cc) xv += 1e-6;
                X[r * DIM + cc] = (float)xv;
            }
        }
    }
    __syncthreads();

    // ---- S3: X2 = X@X ----
    mm_full<false, false, false>(X, X, X2, nullptr, nullptr, 0, 0, 0, 0, 0, t);
    __syncthreads();

    // ---- S4: c0 = exp(X)^T, degree-4 Taylor in one Horner matmul:
    //          exp(X) = I + X + (I/2 + X/6 + X2/24)@X2  (||X||~0.15 -> rem ~6e-7) ----
    mm_full<true, true, true>(nullptr, X2, c0b, X, X2,
                              0.5f, 1.f / 6.f, 1.f / 24.f, 1.f, 1.f, t);
    __syncthreads();

    // ---- S5..S8: squarings (transposed chain closed under squaring) ----
    mm_full<false, false, false>(c0b, c0b, c1b, nullptr, nullptr, 0, 0, 0, 0, 0, t);
    __syncthreads();
    mm_full<false, false, false>(c1b, c1b, c2b, nullptr, nullptr, 0, 0, 0, 0, 0, t);
    __syncthreads();
    mm_full<false, false, false>(c2b, c2b, c3b, nullptr, nullptr, 0, 0, 0, 0, 0, t);
    __syncthreads();
    mm_full<false, false, false>(c3b, c3b, c4b, nullptr, nullptr, 0, 0, 0, 0, 0, t);
    __syncthreads();

    // ---- stage W16 into LDS; z into LDS ----
    #pragma unroll
    for (int q = 0; q < 4; ++q) {
        const int e = q * 4096 + t * 4;
        *reinterpret_cast<float4*>(s_W + e) = *reinterpret_cast<const float4*>(c4b + e);
    }
    if (t < DIM)            s_z[t] = z0r[b * DIM + t];
    else if (t < 2 * DIM)   s_z[t] = z0i[b * DIM + (t - DIM)];
    __syncthreads();

    const int o = t & 127, g = t >> 7;   // 8 groups x 128 output lanes

    // ---- h0: u1 = M z  (slots hold u_{slot+1}) ----
    if (g < 2) {
        float acc = 0.f;
        for (int i = 0; i < DIM; ++i) acc += c0b[i * DIM + o] * s_z[g * DIM + i];
        s_u[(g * 16 + 0) * DIM + o] = acc;
        write_out(outF, b, 0, o, g, acc, interleaved, out_size);
    }
    __syncthreads();

    // ---- h1..h4: doubling history u2; u3,4; u5-8; u9-16 ----
    const float* hw[4] = {c0b, c1b, c2b, c3b};   // M^T, (M^2)^T, (M^4)^T, (M^8)^T
    #pragma unroll
    for (int hs = 0; hs < 4; ++hs) {
        const int nv = 1 << hs;                   // source vector count per comp
        const float* Wg = hw[hs];
        for (int j = g; j < nv * 2; j += 8) {
            const int v = j % nv, c = j / nv;
            float acc = 0.f;
            for (int i = 0; i < DIM; ++i)
                acc += Wg[i * DIM + o] * s_u[(c * 16 + v) * DIM + i];
            s_u[(c * 16 + nv + v) * DIM + o] = acc;
            write_out(outF, b, nv + v, o, c, acc, interleaved, out_size);
        }
        __syncthreads();
    }

    // ---- 7 windows: u_{16w + v + 1} = M^16 * u_{16(w-1) + v + 1}, in-place in LDS ----
    for (int w = 1; w <= 7; ++w) {
        float acc[4] = {0.f, 0.f, 0.f, 0.f};
        for (int i = 0; i < DIM; ++i) {
            const float wv = s_W[i * DIM + o];     // 2-way bank alias: free
            #pragma unroll
            for (int m = 0; m < 4; ++m) {
                const int j = g + 8 * m;           // 32 jobs: c=j>>4, v=j&15
                acc[m] += wv * s_u[((j >> 4) * 16 + (j & 15)) * DIM + i];  // broadcast
            }
        }
        __syncthreads();   // all reads done before in-place overwrite
        #pragma unroll
        for (int m = 0; m < 4; ++m) {
            const int j = g + 8 * m;
            const int c = j >> 4, v = j & 15;
            s_u[(c * 16 + v) * DIM + o] = acc[m];
            write_out(outF, b, 16 * w + v, o, c, acc[m], interleaved, out_size);
        }
        __syncthreads();
    }
}

// ================= host =================
extern "C" void kernel_launch(void* const* d_in, const int* in_sizes, int n_in,
                              void* d_out, int out_size, void* d_ws, size_t ws_size,
                              hipStream_t stream)
{
    (void)in_sizes; (void)n_in; (void)d_ws; (void)ws_size;
    const float* z0r = (const float*)d_in[0];
    const float* z0i = (const float*)d_in[1];
    const float* ts  = (const float*)d_in[2];
    const float* kco = (const float*)d_in[3];
    const float* rco = (const float*)d_in[4];
    const float* alp = (const float*)d_in[5];
    const float* bet = (const float*)d_in[6];
    const float* KB  = (const float*)d_in[7];
    const float* RB  = (const float*)d_in[8];
    float* outF = (float*)d_out;

    const int interleaved = (out_size >= 2 * BATCH * SSTEPS * DIM) ? 1 : 0;

    htg_fused<<<dim3(BATCH), dim3(1024), 0, stream>>>(
        z0r, z0i, ts, kco, rco, alp, bet, KB, RB, outF, interleaved, out_size);
}